// Round 6
// baseline (284.853 us; speedup 1.0000x reference)
//
#include <hip/hip_runtime.h>
#include <cmath>

// SSIM fused kernel, wave-autonomous version (R5 + compiler memory fences).
// Each wave (64 lanes) owns a 64-col x 32-row output tile of one plane and a
// PRIVATE 74-slot LDS row buffer (cols c0-5 .. c0+68). Staging and horizontal
// conv are wave-synchronous: the DS pipe executes a wave's LDS ops in order,
// but the COMPILER sees per-lane addresses (write l+5, read l+k, k!=5) as
// non-aliasing and may reorder across lanes -> R5's 2.4e-3 deterministic
// error. Fix: asm volatile("" ::: "memory") fences bracketing the staging
// writes. Zero runtime cost; no __syncthreads anywhere (no 8-wave convoys).
// Vertical conv via per-thread register ring of 4 quantities:
// conv(a), conv(b), conv(a^2+b^2), conv(ab).

#define IMG_H 512
#define IMG_W 512
#define STRIPE 32
#define NSTR 16
#define NPLANES 48
#define NWAVES (NPLANES * NSTR * 8)    // 6144 waves, 64 cols each
#define NBLOCKS (NWAVES / 4)           // 1536 blocks of 256 threads
#define SSIM_C1 (0.01f * 0.01f)
#define SSIM_C2 (0.03f * 0.03f)

#define WAVE_MEM_FENCE() asm volatile("" ::: "memory")

struct W11 { float w[11]; };

__attribute__((amdgpu_flat_work_group_size(256, 256), amdgpu_waves_per_eu(1)))
__global__ void ssim_main(const float* __restrict__ img1,
                          const float* __restrict__ img2,
                          float* __restrict__ waveSums, W11 wv) {
    __shared__ float2 tb[4][80];   // per-wave private; slots 0..73 used

    const int tid = threadIdx.x;
    const int wia = tid >> 6;      // wave in block
    const int l   = tid & 63;
    const int bid = blockIdx.x;
    const int plane  = bid >> 5;          // 48 planes
    const int rem    = bid & 31;
    const int stripe = rem >> 1;          // 16 row-stripes
    const int half   = rem & 1;           // which 256-col half
    const int c0 = half * 256 + wia * 64; // wave's first column
    const int y0 = stripe * STRIPE;
    const int col = c0 + l;               // own column (always < 512)

    const float* __restrict__ p1 = img1 + (size_t)plane * (IMG_H * IMG_W);
    const float* __restrict__ p2 = img2 + (size_t)plane * (IMG_H * IMG_W);

    float2* buf = tb[wia];

    // halo: lanes 0..4 -> cols c0-5..c0-1 (slots 0..4),
    //       lanes 5..9 -> cols c0+64..c0+68 (slots 69..73)
    const bool hlane  = (l < 10);
    const int  hraw   = (l < 5) ? (c0 - 5 + l) : (c0 + 59 + l);
    const bool hvalid = hlane && (hraw >= 0) && (hraw < IMG_W);
    const int  hcol   = hvalid ? hraw : 0;       // clamped, masked later
    const int  hslot  = (l < 5) ? l : (l + 64);  // 0..4 / 69..73

    float rA[11], rB[11], rS[11], rP[11];  // vertical ring, static-indexed
    float acc = 0.f;
    float pa = 0.f, pb = 0.f, hpa = 0.f, hpb = 0.f;

#define LOAD_ROW(RI) do {                                                   \
    const int ri_ = (RI);                                                   \
    if (ri_ >= 0 && ri_ < IMG_H) {      /* wave-uniform branch */           \
        const size_t off_ = (size_t)ri_ * IMG_W;                            \
        pa = p1[off_ + col]; pb = p2[off_ + col];                           \
        if (hlane) {                                                        \
            const float ta_ = p1[off_ + hcol], tb_ = p2[off_ + hcol];       \
            hpa = hvalid ? ta_ : 0.f; hpb = hvalid ? tb_ : 0.f;             \
        }                                                                   \
    } else { pa = 0.f; pb = 0.f; hpa = 0.f; hpb = 0.f; }                    \
} while (0)

// Stage current row (regs -> LDS), compute own-tap (k=5) from regs, start
// the next row's loads, then do the remaining 10 horizontal taps from LDS.
// Fences: pre-write fence blocks this row's writes from hoisting above the
// PREVIOUS row's ds_reads (WAR); post-write fence blocks this row's ds_reads
// from hoisting above the writes (RAW). HW DS pipe is in-order per wave.
#define STAGE_AND_H(PHASE, RINEXT) do {                                     \
    WAVE_MEM_FENCE();                                                       \
    buf[l + 5] = make_float2(pa, pb);                                       \
    if (hlane) buf[hslot] = make_float2(hpa, hpb);                          \
    WAVE_MEM_FENCE();                                                       \
    float h0_, h1_, h2_, h3_;                                               \
    { const float w_ = wv.w[5];                                             \
      const float sq_ = fmaf(pb, pb, pa * pa);                              \
      const float pr_ = pa * pb;                                            \
      h0_ = w_ * pa; h1_ = w_ * pb; h2_ = w_ * sq_; h3_ = w_ * pr_; }       \
    LOAD_ROW(RINEXT);                                                       \
    _Pragma("unroll")                                                       \
    for (int k_ = 0; k_ < 11; ++k_) {                                       \
        if (k_ != 5) {                                                      \
            const float2 t_ = buf[l + k_];   /* ds_read_b64 */              \
            const float w_ = wv.w[k_];                                      \
            const float sq_ = fmaf(t_.y, t_.y, t_.x * t_.x);                \
            const float pr_ = t_.x * t_.y;                                  \
            h0_ = fmaf(w_, t_.x, h0_); h1_ = fmaf(w_, t_.y, h1_);           \
            h2_ = fmaf(w_, sq_, h2_);  h3_ = fmaf(w_, pr_, h3_);            \
        }                                                                   \
    }                                                                       \
    rA[PHASE] = h0_; rB[PHASE] = h1_;                                       \
    rS[PHASE] = h2_; rP[PHASE] = h3_;                                       \
} while (0)

    LOAD_ROW(y0 - 5);

    // prologue: fill ring phases 0..9 (input rows y0-5 .. y0+4)
#pragma unroll
    for (int i = 0; i < 10; ++i) {
        STAGE_AND_H(i, y0 - 4 + i);
    }

    // main: 32 output rows; phase arithmetic static since outer*11 % 11 == 0
#pragma unroll 1
    for (int outer = 0; outer < 3; ++outer) {
#pragma unroll
        for (int jj = 0; jj < 11; ++jj) {
            const int m = outer * 11 + jj;
            if (m < 32) {                        // wave-uniform guard
                STAGE_AND_H((10 + jj) % 11, (m < 31) ? (y0 + 6 + m) : -1);
                float vA = 0.f, vB = 0.f, vS = 0.f, vP = 0.f;
#pragma unroll
                for (int k = 0; k < 11; ++k) {
                    const int s = (jj + k) % 11; // static per (jj,k)
                    const float w = wv.w[k];
                    vA = fmaf(w, rA[s], vA);
                    vB = fmaf(w, rB[s], vB);
                    vS = fmaf(w, rS[s], vS);
                    vP = fmaf(w, rP[s], vP);
                }
                const float mu11 = vA * vA;
                const float mu22 = vB * vB;
                const float mu12 = vA * vB;
                const float num = fmaf(2.f, mu12, SSIM_C1) *
                                  fmaf(2.f, vP - mu12, SSIM_C2);
                const float d1  = mu11 + mu22;
                const float den = (d1 + SSIM_C1) * ((vS - d1) + SSIM_C2);
                acc = fmaf(num, __builtin_amdgcn_rcpf(den), acc);
            }
        }
    }

#undef LOAD_ROW
#undef STAGE_AND_H

    // wave-level reduction only; one partial per wave (no cross-wave sync)
#pragma unroll
    for (int off = 32; off >= 1; off >>= 1)
        acc += __shfl_down(acc, off, 64);
    if (l == 0) waveSums[bid * 4 + wia] = acc;
}

__global__ void ssim_reduce(const float* __restrict__ ws,
                            float* __restrict__ out) {
    __shared__ double red[16];
    const int t = threadIdx.x;  // 1024 threads
    double a = 0.0;
    for (int i = t; i < NWAVES; i += 1024) a += (double)ws[i];
#pragma unroll
    for (int off = 32; off >= 1; off >>= 1)
        a += __shfl_down(a, off, 64);
    const int wv_ = t >> 6, lane = t & 63;
    if (lane == 0) red[wv_] = a;
    __syncthreads();
    if (t == 0) {
        double s = 0.0;
#pragma unroll
        for (int k = 0; k < 16; ++k) s += red[k];
        out[0] = (float)(s / ((double)NPLANES * IMG_H * IMG_W));
    }
}

extern "C" void kernel_launch(void* const* d_in, const int* in_sizes, int n_in,
                              void* d_out, int out_size, void* d_ws, size_t ws_size,
                              hipStream_t stream) {
    const float* img1 = (const float*)d_in[0];
    const float* img2 = (const float*)d_in[1];
    float* out = (float*)d_out;
    float* wsums = (float*)d_ws;   // 6144 floats = 24 KB scratch

    // Gaussian weights, faithful to reference: center 5.5, sigma 1.5
    W11 wv;
    double g[11], s = 0.0;
    for (int i = 0; i < 11; ++i) {
        const double d = (double)i - 5.5;
        g[i] = exp(-(d * d) / (2.0 * 1.5 * 1.5));
        s += g[i];
    }
    for (int i = 0; i < 11; ++i) wv.w[i] = (float)(g[i] / s);

    ssim_main<<<NBLOCKS, 256, 0, stream>>>(img1, img2, wsums, wv);
    ssim_reduce<<<1, 1024, 0, stream>>>(wsums, out);
}